// Round 2
// baseline (324.253 us; speedup 1.0000x reference)
//
#include <hip/hip_runtime.h>
#include <hip/hip_fp16.h>

typedef _Float16 f16;
typedef _Float16 f16x8 __attribute__((ext_vector_type(8)));
typedef __fp16 h16x2 __attribute__((ext_vector_type(2)));
typedef float f32x4 __attribute__((ext_vector_type(4)));

#define LOG2E 1.4426950408889634f
#define NSL 0.2f

// ---------------- Kernel 1: graph -> transposed bitmask ----------------
// maskT[i][jw] bit b = (graph[jw*32+b][i] > 0)
__global__ __launch_bounds__(256) void k_mask(const int* __restrict__ graph,
                                              unsigned int* __restrict__ maskT) {
    __shared__ unsigned long long bal[4][64];
    int w = threadIdx.x >> 6;
    int lane = threadIdx.x & 63;
    int gw = blockIdx.x * 4 + w;      // 4096 waves, one 64x64 bit tile each
    int ti = gw & 63, tj = gw >> 6;
    int i0 = ti * 64, j0 = tj * 64;
    #pragma unroll 8
    for (int k = 0; k < 64; k++) {
        int g = graph[(j0 + k) * 4096 + i0 + lane];
        unsigned long long b = __ballot(g > 0);
        if (lane == 0) bal[w][k] = b;
    }
    __syncthreads();
    unsigned long long word = 0;
    #pragma unroll 8
    for (int k = 0; k < 64; k++) {
        word |= ((bal[w][k] >> lane) & 1ull) << k;
    }
    uint2 st; st.x = (unsigned int)word; st.y = (unsigned int)(word >> 32);
    *(uint2*)&maskT[(unsigned)(i0 + lane) * 128u + (unsigned)(j0 >> 5)] = st;
}

// ---------------- Kernel 2: fp32 [R][C] -> f16 [C][R] transpose ----------------
__global__ __launch_bounds__(256) void k_transpose(const float* __restrict__ in,
                                                   f16* __restrict__ out, int R, int C) {
    __shared__ float tile[32][33];
    int tx = threadIdx.x & 31, ty = threadIdx.x >> 5;
    int c0 = blockIdx.x * 32, r0 = blockIdx.y * 32;
    for (int rr = ty; rr < 32; rr += 8)
        tile[rr][tx] = in[(r0 + rr) * C + c0 + tx];
    __syncthreads();
    for (int rr = ty; rr < 32; rr += 8)
        out[(size_t)(c0 + rr) * R + r0 + tx] = (f16)tile[tx][rr];
}

// ---------------- Kernel 3: hbT[h][f][j] = sum_m x[j][m] * W[h][m][f]  (f16 out) ----------------
// Computes C^T = Wht(h-slice) @ x^T.  A = Wht rows (f), B = x rows (j), both contiguous.
__global__ __launch_bounds__(256) void k_gemm_h(const float* __restrict__ x,
                                                const f16* __restrict__ Wht,
                                                f16* __restrict__ hbT) {
    int bx = blockIdx.x;
    int h = bx & 7, jb = bx >> 3;
    int j0 = jb * 64;
    int tid = threadIdx.x;
    int w = tid >> 6, lane = tid & 63;
    int ln = lane & 15, q = lane >> 4;
    f32x4 acc[2][4] = {};
    for (int k0 = 0; k0 < 512; k0 += 32) {
        f16x8 a0 = *(const f16x8*)(Wht + (size_t)(w * 32 + ln) * 4096 + h * 512 + k0 + q * 8);
        f16x8 a1 = *(const f16x8*)(Wht + (size_t)(w * 32 + 16 + ln) * 4096 + h * 512 + k0 + q * 8);
        f16x8 bfr[4];
        #pragma unroll
        for (int nt = 0; nt < 4; nt++) {
            const float4* xp = (const float4*)(x + (size_t)(j0 + nt * 16 + ln) * 512 + k0 + q * 8);
            float4 xa = xp[0], xb = xp[1];
            union { f16x8 v; h16x2 p[4]; } u;
            u.p[0] = __builtin_amdgcn_cvt_pkrtz(xa.x, xa.y);
            u.p[1] = __builtin_amdgcn_cvt_pkrtz(xa.z, xa.w);
            u.p[2] = __builtin_amdgcn_cvt_pkrtz(xb.x, xb.y);
            u.p[3] = __builtin_amdgcn_cvt_pkrtz(xb.z, xb.w);
            bfr[nt] = u.v;
        }
        #pragma unroll
        for (int nt = 0; nt < 4; nt++) {
            acc[0][nt] = __builtin_amdgcn_mfma_f32_16x16x32_f16(a0, bfr[nt], acc[0][nt], 0, 0, 0);
            acc[1][nt] = __builtin_amdgcn_mfma_f32_16x16x32_f16(a1, bfr[nt], acc[1][nt], 0, 0, 0);
        }
    }
    #pragma unroll
    for (int mt = 0; mt < 2; mt++)
        #pragma unroll
        for (int nt = 0; nt < 4; nt++) {
            int j = j0 + nt * 16 + ln;
            #pragma unroll
            for (int r = 0; r < 4; r++) {
                int f = w * 32 + mt * 16 + q * 4 + r;
                hbT[(size_t)(h * 128 + f) * 4096 + j] = (f16)acc[mt][nt][r];
            }
        }
}

// ---------------- Kernel 4: a2[h][j] = (h . w_i)*log2e ; b2 likewise ----------------
__global__ __launch_bounds__(256) void k_ab(const f16* __restrict__ hbT,
                                            const float* __restrict__ wi,
                                            const float* __restrict__ wj,
                                            float* __restrict__ a2, float* __restrict__ b2) {
    __shared__ float swi[128], swj[128];
    int b = blockIdx.x;
    int h = b & 7, jc = b >> 3;
    int tid = threadIdx.x;
    if (tid < 128) { swi[tid] = wi[h * 128 + tid]; swj[tid] = wj[h * 128 + tid]; }
    __syncthreads();
    int j = jc * 256 + tid;
    float pa = 0.f, pb = 0.f;
    #pragma unroll 8
    for (int f = 0; f < 128; f++) {
        float v = (float)hbT[(size_t)(h * 128 + f) * 4096 + j];
        pa += v * swi[f];
        pb += v * swj[f];
    }
    a2[h * 4096 + j] = pa * LOG2E;
    b2[h * 4096 + j] = pb * LOG2E;
}

// ---------------- Kernel 5: per-head max + exp tables ----------------
// ABpre[h][i] = {2^(a2 - m2), 2^(0.2 a2 - m2)},  m2 = lrelu(a2 + M2)
// Bpre[h][j]  = {2^(b2), 2^(0.2 b2)},  M2 = max_j b2
__global__ __launch_bounds__(256) void k_prep(const float* __restrict__ a2,
                                              const float* __restrict__ b2,
                                              float* __restrict__ ABpre,
                                              float* __restrict__ Bpre) {
    __shared__ float red[256];
    int h = blockIdx.x, tid = threadIdx.x;
    float m = -1e30f;
    for (int j = tid; j < 4096; j += 256) m = fmaxf(m, b2[h * 4096 + j]);
    red[tid] = m;
    __syncthreads();
    for (int s = 128; s > 0; s >>= 1) {
        if (tid < s) red[tid] = fmaxf(red[tid], red[tid + s]);
        __syncthreads();
    }
    float M2 = red[0];
    for (int j = tid; j < 4096; j += 256) {
        float av = a2[h * 4096 + j];
        float t = av + M2;
        float m2 = fmaxf(t, NSL * t);
        ABpre[2 * (h * 4096 + j)]     = exp2f(av - m2);
        ABpre[2 * (h * 4096 + j) + 1] = exp2f(NSL * av - m2);
        float bv = b2[h * 4096 + j];
        Bpre[2 * (h * 4096 + j)]     = exp2f(bv);
        Bpre[2 * (h * 4096 + j) + 1] = exp2f(NSL * bv);
    }
}

// ---------------- Kernel 6: main fused masked-softmax GEMM + residual + bias ----------------
// Per block: (head h, 64-row i-tile). acc = P_norm @ h + x @ Wr ; P generated in-register.
__global__ __launch_bounds__(256) void k_main(const float* __restrict__ x,
                                              const f16* __restrict__ hbT,
                                              const f16* __restrict__ Wrt,
                                              const unsigned int* __restrict__ maskT,
                                              const float* __restrict__ ABpre,
                                              const float* __restrict__ Bpre,
                                              const float* __restrict__ bias,
                                              float* __restrict__ out) {
    __shared__ f16 hstage[2][128 * 40];
    __shared__ f16 xstage[2][64 * 40];

    int bx = blockIdx.x;
    int h = bx & 7, it = bx >> 3;   // head inner -> XCD-local L2 reuse of hbT slice
    int i0 = it * 64;
    int tid = threadIdx.x;
    int w = tid >> 6, lane = tid & 63;
    int ln = lane & 15, q = lane >> 4;
    int iA = i0 + w * 16 + ln;

    float2 Av = *(const float2*)(ABpre + 2 * (h * 4096 + iA));
    float Ai = Av.x, Ai2 = Av.y;

    const f16x8 onev = {(_Float16)1, (_Float16)1, (_Float16)1, (_Float16)1,
                        (_Float16)1, (_Float16)1, (_Float16)1, (_Float16)1};

    f32x4 acc[8] = {};
    f32x4 accs = {};

    int sf = tid >> 1, shalf = tid & 1;
    const f16* hsrc = hbT + (size_t)(h * 128 + sf) * 4096 + shalf * 16;
    f16* hdst = &hstage[0][0] + sf * 40 + shalf * 16;

    // prologue: stage j-tile 0
    {
        const int4* s = (const int4*)hsrc;
        int4 v0 = s[0], v1 = s[1];
        int4* d = (int4*)hdst;
        d[0] = v0; d[1] = v1;
    }
    __syncthreads();

    int buf = 0;
    for (int kb = 0; kb < 128; kb++) {
        int j0 = kb * 32;
        unsigned mw = maskT[(unsigned)iA * 128u + (unsigned)(j0 >> 5)];
        const float4* bp = (const float4*)(Bpre + 2 * (h * 4096 + j0 + q * 8));
        float4 bq0 = bp[0], bq1 = bp[1], bq2 = bp[2], bq3 = bp[3];

        if (kb < 127) {   // prefetch next j-tile into other buffer
            const int4* s = (const int4*)(hsrc + j0 + 32);
            int4 v0 = s[0], v1 = s[1];
            int4* d = (int4*)(hdst + (buf ^ 1) * (128 * 40));
            d[0] = v0; d[1] = v1;
        }

        // generate masked-P A-fragment: P = max(Ai*Bj, Ai2*B'j), zero if edge absent
        union { f16x8 v; h16x2 p[4]; } af;
        float v0, v1;
        v0 = fmaxf(Ai * bq0.x, Ai2 * bq0.y); v1 = fmaxf(Ai * bq0.z, Ai2 * bq0.w);
        v0 = ((mw >> (q * 8 + 0)) & 1u) ? v0 : 0.f;
        v1 = ((mw >> (q * 8 + 1)) & 1u) ? v1 : 0.f;
        af.p[0] = __builtin_amdgcn_cvt_pkrtz(v0, v1);
        v0 = fmaxf(Ai * bq1.x, Ai2 * bq1.y); v1 = fmaxf(Ai * bq1.z, Ai2 * bq1.w);
        v0 = ((mw >> (q * 8 + 2)) & 1u) ? v0 : 0.f;
        v1 = ((mw >> (q * 8 + 3)) & 1u) ? v1 : 0.f;
        af.p[1] = __builtin_amdgcn_cvt_pkrtz(v0, v1);
        v0 = fmaxf(Ai * bq2.x, Ai2 * bq2.y); v1 = fmaxf(Ai * bq2.z, Ai2 * bq2.w);
        v0 = ((mw >> (q * 8 + 4)) & 1u) ? v0 : 0.f;
        v1 = ((mw >> (q * 8 + 5)) & 1u) ? v1 : 0.f;
        af.p[2] = __builtin_amdgcn_cvt_pkrtz(v0, v1);
        v0 = fmaxf(Ai * bq3.x, Ai2 * bq3.y); v1 = fmaxf(Ai * bq3.z, Ai2 * bq3.w);
        v0 = ((mw >> (q * 8 + 6)) & 1u) ? v0 : 0.f;
        v1 = ((mw >> (q * 8 + 7)) & 1u) ? v1 : 0.f;
        af.p[3] = __builtin_amdgcn_cvt_pkrtz(v0, v1);

        const f16* hb = &hstage[buf][0];
        #pragma unroll
        for (int nt = 0; nt < 8; nt++) {
            f16x8 bf = *(const f16x8*)(hb + (nt * 16 + ln) * 40 + q * 8);
            acc[nt] = __builtin_amdgcn_mfma_f32_16x16x32_f16(af.v, bf, acc[nt], 0, 0, 0);
        }
        accs = __builtin_amdgcn_mfma_f32_16x16x32_f16(af.v, onev, accs, 0, 0, 0);  // row sums

        __syncthreads();
        buf ^= 1;
    }

    // normalize by softmax denominator (rows q*4+r match C/D layout)
    float rl[4];
    #pragma unroll
    for (int r = 0; r < 4; r++) rl[r] = 1.0f / accs[r];
    #pragma unroll
    for (int nt = 0; nt < 8; nt++)
        #pragma unroll
        for (int r = 0; r < 4; r++) acc[nt][r] *= rl[r];

    // ------- residual: acc += x @ W_r (K=512) -------
    int xrow = tid >> 2, xq = tid & 3;
    const f16* wsrc = Wrt + (size_t)(h * 128 + sf) * 512 + shalf * 16;

    {
        const int4* s = (const int4*)wsrc;
        int4 v0 = s[0], v1 = s[1];
        int4* d = (int4*)hdst;
        d[0] = v0; d[1] = v1;
        const float4* xs = (const float4*)(x + (size_t)(i0 + xrow) * 512 + xq * 8);
        float4 u0 = xs[0], u1 = xs[1];
        union { int4 i4; h16x2 p[4]; } px;
        px.p[0] = __builtin_amdgcn_cvt_pkrtz(u0.x, u0.y);
        px.p[1] = __builtin_amdgcn_cvt_pkrtz(u0.z, u0.w);
        px.p[2] = __builtin_amdgcn_cvt_pkrtz(u1.x, u1.y);
        px.p[3] = __builtin_amdgcn_cvt_pkrtz(u1.z, u1.w);
        *(int4*)(&xstage[0][0] + xrow * 40 + xq * 8) = px.i4;
    }
    __syncthreads();
    buf = 0;
    for (int kb = 0; kb < 16; kb++) {
        int m0 = kb * 32;
        if (kb < 15) {
            const int4* s = (const int4*)(wsrc + m0 + 32);
            int4 v0 = s[0], v1 = s[1];
            int4* d = (int4*)(hdst + (buf ^ 1) * (128 * 40));
            d[0] = v0; d[1] = v1;
            const float4* xs = (const float4*)(x + (size_t)(i0 + xrow) * 512 + m0 + 32 + xq * 8);
            float4 u0 = xs[0], u1 = xs[1];
            union { int4 i4; h16x2 p[4]; } px;
            px.p[0] = __builtin_amdgcn_cvt_pkrtz(u0.x, u0.y);
            px.p[1] = __builtin_amdgcn_cvt_pkrtz(u0.z, u0.w);
            px.p[2] = __builtin_amdgcn_cvt_pkrtz(u1.x, u1.y);
            px.p[3] = __builtin_amdgcn_cvt_pkrtz(u1.z, u1.w);
            *(int4*)(&xstage[buf ^ 1][0] + xrow * 40 + xq * 8) = px.i4;
        }
        f16x8 afx = *(const f16x8*)(&xstage[buf][0] + (w * 16 + ln) * 40 + q * 8);
        const f16* hb = &hstage[buf][0];
        #pragma unroll
        for (int nt = 0; nt < 8; nt++) {
            f16x8 bf = *(const f16x8*)(hb + (nt * 16 + ln) * 40 + q * 8);
            acc[nt] = __builtin_amdgcn_mfma_f32_16x16x32_f16(afx, bf, acc[nt], 0, 0, 0);
        }
        __syncthreads();
        buf ^= 1;
    }

    // epilogue: + bias, store fp32
    #pragma unroll
    for (int nt = 0; nt < 8; nt++) {
        int col = h * 128 + nt * 16 + ln;
        float bv = bias[col];
        #pragma unroll
        for (int r = 0; r < 4; r++) {
            int i = i0 + w * 16 + q * 4 + r;
            out[(size_t)i * 1024 + col] = acc[nt][r] + bv;
        }
    }
}

extern "C" void kernel_launch(void* const* d_in, const int* in_sizes, int n_in,
                              void* d_out, int out_size, void* d_ws, size_t ws_size,
                              hipStream_t stream) {
    (void)in_sizes; (void)n_in; (void)out_size; (void)ws_size;
    const float* x     = (const float*)d_in[0];
    const int*   graph = (const int*)d_in[1];
    const float* W     = (const float*)d_in[2];
    const float* wi    = (const float*)d_in[3];
    const float* wj    = (const float*)d_in[4];
    const float* Wr    = (const float*)d_in[5];
    const float* bias  = (const float*)d_in[6];
    float* out = (float*)d_out;

    char* ws = (char*)d_ws;
    unsigned int* maskT = (unsigned int*)ws;              // 2 MB  [4096][128] bits
    f16* hbT   = (f16*)(ws + (2u << 20));                 // 8 MB  [8][128][4096]
    f16* Wht   = (f16*)(ws + (10u << 20));                // 1 MB  [128][4096]  (W^T)
    f16* Wrt   = (f16*)(ws + (11u << 20));                // 1 MB  [1024][512]  (W_r^T)
    float* a2    = (float*)(ws + (12u << 20));            // 128 KB
    float* b2    = a2 + 8 * 4096;                         // 128 KB
    float* ABpre = b2 + 8 * 4096;                         // 256 KB (float2)
    float* Bpre  = ABpre + 2 * 8 * 4096;                  // 256 KB (float2)

    hipLaunchKernelGGL(k_mask, dim3(1024), dim3(256), 0, stream, graph, maskT);
    hipLaunchKernelGGL(k_transpose, dim3(4, 128), dim3(256), 0, stream, W, Wht, 4096, 128);
    hipLaunchKernelGGL(k_transpose, dim3(32, 16), dim3(256), 0, stream, Wr, Wrt, 512, 1024);
    hipLaunchKernelGGL(k_gemm_h, dim3(512), dim3(256), 0, stream, x, Wht, hbT);
    hipLaunchKernelGGL(k_ab, dim3(128), dim3(256), 0, stream, hbT, wi, wj, a2, b2);
    hipLaunchKernelGGL(k_prep, dim3(8), dim3(256), 0, stream, a2, b2, ABpre, Bpre);
    hipLaunchKernelGGL(k_main, dim3(512), dim3(256), 0, stream, x, hbT, Wrt, maskT, ABpre, Bpre,
                       bias, out);
}